// Round 15
// baseline (21710.706 us; speedup 1.0000x reference)
//
#include <hip/hip_runtime.h>
#include <stdint.h>

#define B_TOT 32768
#define A_N   32
#define D_N   64
#define H_N   128
#define KD    128   // 2*D
#define BT    16
#define NT    256

// ---------------- K2: rewards[b,a]  (f64 chain, hctx fused) -----------------
__global__ __launch_bounds__(NT)
void k2_rewards(const int* __restrict__ x, const float* __restrict__ cemb,
                const float* __restrict__ W1, const float* __restrict__ b1,
                const float* __restrict__ W2, const float* __restrict__ b2,
                const float* __restrict__ Wr1, const float* __restrict__ br1,
                const float* __restrict__ Wr2, double* __restrict__ rew)
{
  __shared__ double ctxd [BT][130];
  __shared__ double hctxd[BT][130];
  __shared__ double hidd [BT][130];
  __shared__ double predd[BT][66];
  __shared__ double part [BT][17];
  const int tid = threadIdx.x, b0 = blockIdx.x * BT, a = blockIdx.y;
  for (int e = tid; e < BT*KD; e += NT) {
    int r = e >> 7, i = e & 127;
    int xi = x[(b0 + r)*2 + (i >> 6)];
    ctxd[r][i] = (double)cemb[(size_t)xi*D_N + (i & 63)];
  }
  __syncthreads();
  const int r = tid >> 4, g = tid & 15;
  // hctx[r,h] = ctx . Wr1[h, :128]   and   hidden[r,h] = ctx . W1[a,h,:] + b1
  for (int hh = 0; hh < 8; ++hh) {
    int h = g + 16*hh;
    const float* wc = Wr1 + (size_t)h*192;
    const float* w1 = W1 + ((size_t)a*H_N + h)*KD;
    double ac = 0.0, ah = (double)b1[a*H_N + h];
    for (int i = 0; i < KD; ++i) {
      double c = ctxd[r][i];
      ac = fma(c, (double)wc[i], ac);
      ah = fma(c, (double)w1[i], ah);
    }
    hctxd[r][h] = ac;
    hidd[r][h]  = ah;
  }
  __syncthreads();
  // preds[r,d] = hidden . W2[a,d,:] + b2[a,d]
  for (int dd = 0; dd < 4; ++dd) {
    int d = g + 16*dd;
    const float* w = W2 + ((size_t)a*D_N + d)*H_N;
    double acc = (double)b2[a*D_N + d];
    for (int h = 0; h < H_N; ++h) acc = fma(hidd[r][h], (double)w[h], acc);
    predd[r][d] = acc;
  }
  __syncthreads();
  // partial rewards over this thread's 8 h-columns
  double sv = 0.0;
  for (int hh = 0; hh < 8; ++hh) {
    int h = g + 16*hh;
    const float* wp = Wr1 + (size_t)h*192 + 128;
    double pp = 0.0;
    for (int d = 0; d < D_N; ++d) pp = fma(predd[r][d], (double)wp[d], pp);
    double t = hctxd[r][h] + pp + (double)br1[h];
    double gr = (t > 0.0) ? t : ((t == t) ? 0.0 : t);   // NaN-propagating relu
    sv = fma(gr, (double)Wr2[h], sv);
  }
  part[r][g] = sv;
  __syncthreads();
  if (tid < BT) {
    double s2 = 0.0;
    for (int q = 0; q < 16; ++q) s2 += part[tid][q];
    rew[(size_t)(b0 + tid)*A_N + a] = s2;
  }
}

// ---------------- K3: sel[b] = np-exact argmin over 32 rewards --------------
__global__ __launch_bounds__(NT)
void k3_argmin(const double* __restrict__ rew, int* __restrict__ sel)
{
  int b = blockIdx.x * NT + threadIdx.x;
  if (b >= B_TOT) return;
  const double* rr = rew + (size_t)b*A_N;
  double best = rr[0]; int idx = 0;
  for (int a = 1; a < A_N; ++a) {
    double v = rr[a];
    // np.argmin: first NaN wins forever; otherwise strict < (first-min ties)
    if (!(best != best) && ((v != v) || (v < best))) { best = v; idx = a; }
  }
  sel[b] = idx;
}

// ---------------- K4: out_r[b,:] = preds[b, sel[b], :]  (f32 out) -----------
__global__ __launch_bounds__(NT)
void k4_out(const int* __restrict__ x, const float* __restrict__ cemb,
            const float* __restrict__ W1, const float* __restrict__ b1,
            const float* __restrict__ W2, const float* __restrict__ b2,
            const int* __restrict__ sel, float* __restrict__ out_r)
{
  __shared__ double ctxd[BT][130];
  __shared__ double hidd[BT][130];
  __shared__ int sels[BT];
  const int tid = threadIdx.x, b0 = blockIdx.x * BT;
  for (int e = tid; e < BT*KD; e += NT) {
    int r = e >> 7, i = e & 127;
    int xi = x[(b0 + r)*2 + (i >> 6)];
    ctxd[r][i] = (double)cemb[(size_t)xi*D_N + (i & 63)];
  }
  if (tid < BT) sels[tid] = sel[b0 + tid];
  __syncthreads();
  const int r = tid >> 4, g = tid & 15;
  const int a = sels[r];
  for (int hh = 0; hh < 8; ++hh) {
    int h = g + 16*hh;
    const float* w = W1 + ((size_t)a*H_N + h)*KD;
    double acc = (double)b1[a*H_N + h];
    for (int i = 0; i < KD; ++i) acc = fma(ctxd[r][i], (double)w[i], acc);
    hidd[r][h] = acc;
  }
  __syncthreads();
  for (int dd = 0; dd < 4; ++dd) {
    int d = g + 16*dd;
    const float* w = W2 + ((size_t)a*D_N + d)*H_N;
    double acc = (double)b2[a*D_N + d];
    for (int h = 0; h < H_N; ++h) acc = fma(hidd[r][h], (double)w[h], acc);
    out_r[(size_t)(b0 + r)*D_N + d] = (float)acc;   // FLOAT32 output
  }
}

// ---------------- K5: wemb gather (f32 out) ---------------------------------
__global__ __launch_bounds__(NT)
void k5_wemb(const int* __restrict__ y, const float* __restrict__ wtab,
             float* __restrict__ out)
{
  int i = blockIdx.x * NT + threadIdx.x;   // over B*64
  int b = i >> 6, d = i & 63;
  out[i] = wtab[(size_t)y[b]*D_N + d];     // FLOAT32 output
}

extern "C" void kernel_launch(void* const* d_in, const int* in_sizes, int n_in,
                              void* d_out, int out_size, void* d_ws, size_t ws_size,
                              hipStream_t stream) {
  (void)in_sizes; (void)n_in; (void)out_size; (void)ws_size;
  // Doc-order bindings (R15: all prior "falsifications" were artifacts of the
  // bf16-output dtype error; doc semantics restored).
  const int*   x    = (const int*)d_in[0];
  const int*   y    = (const int*)d_in[1];
  const float* cemb = (const float*)d_in[2];
  const float* wemb = (const float*)d_in[3];
  const float* W1   = (const float*)d_in[4];
  const float* b1   = (const float*)d_in[5];
  const float* W2   = (const float*)d_in[6];
  const float* b2   = (const float*)d_in[7];
  const float* Wr1  = (const float*)d_in[8];
  const float* br1  = (const float*)d_in[9];
  const float* Wr2  = (const float*)d_in[10];
  // br2 (d_in[11]): constant shift of all rewards -> argmin-invariant; unused.

  // ws: rew f64[B][32] @0 (8 MiB); sel i32[B] @8MiB (128 KiB)
  double* ws_rew = (double*)d_ws;
  int*    ws_sel = (int*)((char*)d_ws + (8u << 20));

  float* out_r    = (float*)d_out;                    // [B][64] f32
  float* out_wemb = out_r + (size_t)B_TOT * D_N;      // [B][64] f32

  k2_rewards<<<dim3(B_TOT/BT, A_N), dim3(NT), 0, stream>>>(x, cemb, W1, b1, W2, b2,
                                                           Wr1, br1, Wr2, ws_rew);
  k3_argmin <<<dim3(B_TOT/NT),      dim3(NT), 0, stream>>>(ws_rew, ws_sel);
  k4_out    <<<dim3(B_TOT/BT),      dim3(NT), 0, stream>>>(x, cemb, W1, b1, W2, b2,
                                                           ws_sel, out_r);
  k5_wemb   <<<dim3(B_TOT*D_N/NT),  dim3(NT), 0, stream>>>(y, wemb, out_wemb);
}